// Round 18
// baseline (91.554 us; speedup 1.0000x reference)
//
#include <hip/hip_runtime.h>
#include <hip/hip_bf16.h>

#define ENC 15
#define INV2PI 0.15915494309189535f

typedef __attribute__((ext_vector_type(4))) float f32x4;
typedef __attribute__((ext_vector_type(8))) short s16x8;
typedef __attribute__((ext_vector_type(4))) short s16x4;

static __device__ __forceinline__ short f2bf(float v) {
    __hip_bfloat16 h = __float2bfloat16(v);
    return __builtin_bit_cast(short, h);
}

// Activation sin on PRE-SCALED accumulators (1/2pi folded into W1/W2/b1/b2).
// Compiler-visible intrinsic so the CDNA4 trans-op use-hazard is handled.
static __device__ __forceinline__ float sin_act(float x) {
    return __builtin_amdgcn_sinf(x);
}

// Compiler-only ordering (r16/r17-proven): same-wave DS RAW is in-order.
#define WAVE_ORDER() do { \
    asm volatile("" ::: "memory"); \
    __builtin_amdgcn_sched_barrier(0); \
} while (0)

// ---- weight prep (r17-identical) ----
// ws (bf16):
//   W1b [128][32] @ 0     = bf16(W1 * INV2PI), k padded 18->32
//   W2s [16384]  @ 4096   = bf16(W2[p ^ s(p)] * INV2PI), s(p)=((p>>7)&7)<<3
__global__ void NSC_prep_kernel(const float* __restrict__ W1,
                                const float* __restrict__ W2,
                                __hip_bfloat16* __restrict__ ws) {
    int t = blockIdx.x * 256 + threadIdx.x;
    if (t < 4096) {
        int row = t >> 5, k = t & 31;
        float v = (k < 18) ? W1[row * 18 + k] * INV2PI : 0.0f;
        ws[t] = __float2bfloat16(v);
    } else if (t < 20480) {
        int p = t - 4096;
        int l = p ^ (((p >> 7) & 7) << 3);
        ws[t] = __float2bfloat16(W2[l] * INV2PI);
    }
}

// r17 base with ONE change: TWO complexes per block (grid halved to 1024).
// W2s is staged + synced once (cc=0); complex cc=1 runs with NO barrier —
// X/h rows are wave-private and the X-overwrite vs prior ks=3 hb reads is
// same-wave DS-in-order (WAVE_ORDER at loop top). Complex 2's waves drift
// into staggered phases -> cross-wave VALU/MFMA/LDS overlap (m114).
// Per-complex math bit-identical to r17 (canary: absmax == 0.03125).
// LDS map: [0,32768) W2s ; [32768,49152) slice0 (X, then h ks=1,3) ;
//          [49152,65536) slice1 (h ks=0,2).
__global__ __launch_bounds__(256, 2)
void NSC_59133109732095_kernel(
    const float* __restrict__ points,
    const float* __restrict__ encodings,
    const float* __restrict__ b1,
    const float* __restrict__ b2,
    const float* __restrict__ W3,
    const float* __restrict__ b3,
    const int*   __restrict__ complexes,
    const __hip_bfloat16* __restrict__ ws,
    float* __restrict__ out0,
    float* __restrict__ out1,
    float* __restrict__ out2)
{
    __shared__ __align__(16) char smem[65536];
    char* W2s = smem;            // 32 KB pre-swizzled W2 (linear stage)
    char* Xb  = smem + 32768;    // slice0: X rows [256][64 B]

    const int blk  = blockIdx.x;
    const int tid  = threadIdx.x;
    const int lane = tid & 63;
    const int wv   = tid >> 6;
    const int g    = lane >> 4;
    const int r16  = lane & 15;

    const __hip_bfloat16* W1b = ws;
    const char* ws2b = (const char*)(ws + 4096);

    // ---- stage W2s loads early (hidden under first phase 0) ----
    s16x8 stg[8];
    #pragma unroll
    for (int i = 0; i < 8; ++i)
        stg[i] = *(const s16x8*)(ws2b + i * 4096 + tid * 16);

    #pragma unroll 1
    for (int cc = 0; cc < 2; ++cc) {
        const int c = blk * 2 + cc;

        WAVE_ORDER();   // order prior complex's slice reads vs new X writes

        // ---- phase 0: per-thread bilinear interp, pixel = tid ----
        const int pi = tid >> 4, pj = tid & 15;
        const float ui = (float)pi * (1.0f / 15.0f);
        const float uj = (float)pj * (1.0f / 15.0f);
        const float w00 = (1.0f - ui) * (1.0f - uj), w01 = (1.0f - ui) * uj;
        const float w10 = ui * (1.0f - uj),          w11 = ui * uj;
        const int v0 = complexes[c * 4 + 0], v1 = complexes[c * 4 + 1];
        const int v2 = complexes[c * 4 + 2], v3 = complexes[c * 4 + 3];

        float p[3];
        #pragma unroll
        for (int f = 0; f < 3; ++f)
            p[f] = w00 * points[v0 * 3 + f] + w01 * points[v1 * 3 + f]
                 + w10 * points[v2 * 3 + f] + w11 * points[v3 * 3 + f];

        float Xf[18];
        #pragma unroll
        for (int k = 0; k < ENC; ++k)
            Xf[k] = w00 * encodings[v0 * ENC + k] + w01 * encodings[v1 * ENC + k]
                  + w10 * encodings[v2 * ENC + k] + w11 * encodings[v3 * ENC + k];
        #pragma unroll
        for (int f = 0; f < 3; ++f) Xf[ENC + f] = __sinf(p[f]);   // unscaled

        // write X row (32 bf16 zero-padded), 8-bank swizzle
        #pragma unroll
        for (int ch = 0; ch < 4; ++ch) {
            s16x8 v;
            #pragma unroll
            for (int i = 0; i < 8; ++i) {
                int k = ch * 8 + i;
                v[i] = (k < 18) ? f2bf(Xf[k]) : (short)0;
            }
            *(s16x8*)(Xb + tid * 64 + ((ch * 16) ^ (((tid >> 1) & 3) << 4))) = v;
        }

        if (cc == 0) {
            // write staged W2 chunks (linear), once per block
            #pragma unroll
            for (int i = 0; i < 8; ++i)
                *(s16x8*)(W2s + i * 4096 + tid * 16) = stg[i];
            __syncthreads();   // W2s (block-shared) visible; only barrier
        } else {
            WAVE_ORDER();      // X visible (wave-private rows)
        }

        // ---- read X B-frags once ----
        s16x8 bx[4];
        #pragma unroll
        for (int n = 0; n < 4; ++n) {
            int px = wv * 64 + n * 16 + r16;
            bx[n] = *(const s16x8*)(Xb + px * 64 + ((g * 16) ^ (((px >> 1) & 3) << 4)));
        }

        // ---- init layer-2 accumulators with scaled biases ----
        f32x4 acc2[8][4];
        #pragma unroll
        for (int m = 0; m < 8; ++m) {
            f32x4 bv = *(const f32x4*)(b2 + m * 16 + g * 4);
            #pragma unroll
            for (int r = 0; r < 4; ++r) bv[r] *= INV2PI;
            #pragma unroll
            for (int n = 0; n < 4; ++n) acc2[m][n] = bv;
        }

        // ---- prologue: layer-1 pair for ks=0 ----
        f32x4 accp[2][4];
        #pragma unroll
        for (int mm = 0; mm < 2; ++mm) {
            f32x4 bv = *(const f32x4*)(b1 + mm * 16 + g * 4);
            #pragma unroll
            for (int r = 0; r < 4; ++r) bv[r] *= INV2PI;
            #pragma unroll
            for (int n = 0; n < 4; ++n) accp[mm][n] = bv;
            s16x8 a1 = *(const s16x8*)(W1b + (mm * 16 + r16) * 32 + g * 8);
            #pragma unroll
            for (int n = 0; n < 4; ++n)
                accp[mm][n] = __builtin_amdgcn_mfma_f32_16x16x32_bf16(a1, bx[n], accp[mm][n], 0, 0, 0);
        }

        // ---- main ks pipeline (double-buffered h-slices) ----
        #pragma unroll
        for (int ks = 0; ks < 4; ++ks) {
            char* hsl = smem + 32768 + (1 - (ks & 1)) * 16384;

            // h1 slice = sin_act(accp) -> bf16
            s16x4 hv[2][4];
            #pragma unroll
            for (int mm = 0; mm < 2; ++mm)
                #pragma unroll
                for (int n = 0; n < 4; ++n)
                    #pragma unroll
                    for (int r = 0; r < 4; ++r)
                        hv[mm][n][r] = f2bf(sin_act(accp[mm][n][r]));

            #pragma unroll
            for (int mm = 0; mm < 2; ++mm)
                #pragma unroll
                for (int n = 0; n < 4; ++n) {
                    int px = wv * 64 + n * 16 + r16;
                    *(s16x4*)(hsl + px * 64 + ((mm * 32 + g * 8) ^ (((px >> 1) & 3) << 4))) = hv[mm][n];
                }
            WAVE_ORDER();   // same-wave DS RAW; compiler ordering only

            s16x8 hb[4];
            #pragma unroll
            for (int n = 0; n < 4; ++n) {
                int px = wv * 64 + n * 16 + r16;
                hb[n] = *(const s16x8*)(hsl + px * 64 + ((g * 16) ^ (((px >> 1) & 3) << 4)));
            }

            // issue next L1 pair before the L2 bulk (overlap material)
            if (ks < 3) {
                #pragma unroll
                for (int mm = 0; mm < 2; ++mm) {
                    int m1 = (ks + 1) * 2 + mm;
                    f32x4 bv = *(const f32x4*)(b1 + m1 * 16 + g * 4);
                    #pragma unroll
                    for (int r = 0; r < 4; ++r) bv[r] *= INV2PI;
                    #pragma unroll
                    for (int n = 0; n < 4; ++n) accp[mm][n] = bv;
                    s16x8 a1 = *(const s16x8*)(W1b + (m1 * 16 + r16) * 32 + g * 8);
                    #pragma unroll
                    for (int n = 0; n < 4; ++n)
                        accp[mm][n] = __builtin_amdgcn_mfma_f32_16x16x32_bf16(a1, bx[n], accp[mm][n], 0, 0, 0);
                }
            }

            // layer-2 MFMAs; a2 from LDS (swizzled ds_read_b128)
            #pragma unroll
            for (int hf = 0; hf < 2; ++hf) {
                s16x8 a2[4];
                #pragma unroll
                for (int mi = 0; mi < 4; ++mi) {
                    int row = (hf * 4 + mi) * 16 + r16;
                    int L   = row * 256 + ks * 64 + g * 16;
                    a2[mi] = *(const s16x8*)(W2s + (L ^ ((r16 & 7) << 4)));
                }
                #pragma unroll
                for (int mi = 0; mi < 4; ++mi)
                    #pragma unroll
                    for (int n = 0; n < 4; ++n)
                        acc2[hf * 4 + mi][n] = __builtin_amdgcn_mfma_f32_16x16x32_bf16(
                            a2[mi], hb[n], acc2[hf * 4 + mi][n], 0, 0, 0);
            }
        }

        // ---- layer 3 in registers ----
        float pf0[4] = {0.f, 0.f, 0.f, 0.f};
        float pf1[4] = {0.f, 0.f, 0.f, 0.f};
        float pf2[4] = {0.f, 0.f, 0.f, 0.f};
        #pragma unroll
        for (int m = 0; m < 8; ++m) {
            float s2[4][4];
            #pragma unroll
            for (int n = 0; n < 4; ++n)
                #pragma unroll
                for (int r = 0; r < 4; ++r)
                    s2[n][r] = sin_act(acc2[m][n][r]);
            f32x4 w3a = *(const f32x4*)(W3 + 0 * 128 + m * 16 + g * 4);
            f32x4 w3b = *(const f32x4*)(W3 + 1 * 128 + m * 16 + g * 4);
            f32x4 w3c = *(const f32x4*)(W3 + 2 * 128 + m * 16 + g * 4);
            #pragma unroll
            for (int n = 0; n < 4; ++n)
                #pragma unroll
                for (int r = 0; r < 4; ++r) {
                    pf0[n] = fmaf(s2[n][r], w3a[r], pf0[n]);
                    pf1[n] = fmaf(s2[n][r], w3b[r], pf1[n]);
                    pf2[n] = fmaf(s2[n][r], w3c[r], pf2[n]);
                }
        }
        {
            const float b30 = b3[0], b31 = b3[1], b32 = b3[2];
            #pragma unroll
            for (int n = 0; n < 4; ++n) {
                float v0r = pf0[n]; v0r += __shfl_xor(v0r, 16); v0r += __shfl_xor(v0r, 32);
                float v1r = pf1[n]; v1r += __shfl_xor(v1r, 16); v1r += __shfl_xor(v1r, 32);
                float v2r = pf2[n]; v2r += __shfl_xor(v2r, 16); v2r += __shfl_xor(v2r, 32);
                if (g == n) {
                    float x0 = v0r + b30;
                    float x1 = v1r + b31;
                    float x2 = v2r + b32;
                    const int base = (c * 256 + tid) * 3;
                    out0[base + 0] = p[0] + x0;
                    out0[base + 1] = p[1] + x1;
                    out0[base + 2] = p[2] + x2;
                    out1[base + 0] = x0;
                    out1[base + 1] = x1;
                    out1[base + 2] = x2;
                }
            }
        }
    }
    if (blk == 0 && tid == 0) out2[0] = 1.0f;
}

extern "C" void kernel_launch(void* const* d_in, const int* in_sizes, int n_in,
                              void* d_out, int out_size, void* d_ws, size_t ws_size,
                              hipStream_t stream) {
    const float* points    = (const float*)d_in[0];
    const float* encodings = (const float*)d_in[1];
    const float* W1        = (const float*)d_in[2];
    const float* b1        = (const float*)d_in[3];
    const float* W2        = (const float*)d_in[4];
    const float* b2        = (const float*)d_in[5];
    const float* W3        = (const float*)d_in[6];
    const float* b3        = (const float*)d_in[7];
    const int*   complexes = (const int*)d_in[8];

    const int C  = in_sizes[8] / 4;          // 2048
    const int N3 = C * 256 * 3;              // 1,572,864

    float* out0 = (float*)d_out;
    float* out1 = out0 + N3;
    float* out2 = out1 + N3;

    __hip_bfloat16* ws = (__hip_bfloat16*)d_ws;  // needs 40960 B

    NSC_prep_kernel<<<80, 256, 0, stream>>>(W1, W2, ws);
    NSC_59133109732095_kernel<<<C / 2, 256, 0, stream>>>(
        points, encodings, b1, b2, W3, b3, complexes, ws, out0, out1, out2);
}

// Round 19
// 61.134 us; speedup vs baseline: 1.4976x; 1.4976x over previous
//
#include <hip/hip_runtime.h>
#include <hip/hip_bf16.h>

#define ENC 15
#define INV2PI 0.15915494309189535f

typedef __attribute__((ext_vector_type(4))) float f32x4;
typedef __attribute__((ext_vector_type(8))) short s16x8;
typedef __attribute__((ext_vector_type(4))) short s16x4;

static __device__ __forceinline__ short f2bf(float v) {
    __hip_bfloat16 h = __float2bfloat16(v);
    return __builtin_bit_cast(short, h);
}

// Activation sin on PRE-SCALED accumulators (1/2pi folded into W1/W2/b1/b2).
static __device__ __forceinline__ float sin_act(float x) {
    return __builtin_amdgcn_sinf(x);
}

// Compiler-only ordering (r16/r17-proven): same-wave DS RAW is in-order.
#define WAVE_ORDER() do { \
    asm volatile("" ::: "memory"); \
    __builtin_amdgcn_sched_barrier(0); \
} while (0)

// ---- weight prep (r17-identical) ----
// ws (bf16):
//   W1b [128][32] @ 0     = bf16(W1 * INV2PI), k padded 18->32
//   W2s [16384]  @ 4096   = bf16(W2[p ^ s(p)] * INV2PI), s(p)=((p>>7)&7)<<3
__global__ void NSC_prep_kernel(const float* __restrict__ W1,
                                const float* __restrict__ W2,
                                __hip_bfloat16* __restrict__ ws) {
    int t = blockIdx.x * 256 + threadIdx.x;
    if (t < 4096) {
        int row = t >> 5, k = t & 31;
        float v = (k < 18) ? W1[row * 18 + k] * INV2PI : 0.0f;
        ws[t] = __float2bfloat16(v);
    } else if (t < 20480) {
        int p = t - 4096;
        int l = p ^ (((p >> 7) & 7) << 3);
        ws[t] = __float2bfloat16(W2[l] * INV2PI);
    }
}

// Two complexes per block (grid 1024), W2s staged STRICTLY BEFORE the cc
// loop so the staging registers die at loop entry (r18 regressed because
// stg[8] stayed live across both complexes -> 47 MB scratch spill).
// Inside the loop: byte-identical r17 per-complex body; no barriers after
// the initial one (X/h rows wave-private; same-wave DS-in-order).
// LDS map: [0,32768) W2s ; [32768,49152) slice0 (X, then h ks=1,3) ;
//          [49152,65536) slice1 (h ks=0,2).
// Canaries: absmax == 0.03125, FETCH ~1.7 MB, VGPR <= 128.
__global__ __launch_bounds__(256, 2)
void NSC_59133109732095_kernel(
    const float* __restrict__ points,
    const float* __restrict__ encodings,
    const float* __restrict__ b1,
    const float* __restrict__ b2,
    const float* __restrict__ W3,
    const float* __restrict__ b3,
    const int*   __restrict__ complexes,
    const __hip_bfloat16* __restrict__ ws,
    float* __restrict__ out0,
    float* __restrict__ out1,
    float* __restrict__ out2)
{
    __shared__ __align__(16) char smem[65536];
    char* W2s = smem;            // 32 KB pre-swizzled W2 (linear stage)
    char* Xb  = smem + 32768;    // slice0: X rows [256][64 B]

    const int blk  = blockIdx.x;
    const int tid  = threadIdx.x;
    const int lane = tid & 63;
    const int wv   = tid >> 6;
    const int g    = lane >> 4;
    const int r16  = lane & 15;

    const __hip_bfloat16* W1b = ws;
    const char* ws2b = (const char*)(ws + 4096);

    // ---- stage W2s BEFORE the loop; stg dies here ----
    {
        s16x8 stg[8];
        #pragma unroll
        for (int i = 0; i < 8; ++i)
            stg[i] = *(const s16x8*)(ws2b + i * 4096 + tid * 16);
        #pragma unroll
        for (int i = 0; i < 8; ++i)
            *(s16x8*)(W2s + i * 4096 + tid * 16) = stg[i];
    }
    __syncthreads();   // W2s visible; the block's only barrier

    #pragma unroll 1
    for (int cc = 0; cc < 2; ++cc) {
        const int c = blk * 2 + cc;

        WAVE_ORDER();   // order prior complex's slice reads vs new X writes

        // ---- phase 0: per-thread bilinear interp, pixel = tid ----
        const int pi = tid >> 4, pj = tid & 15;
        const float ui = (float)pi * (1.0f / 15.0f);
        const float uj = (float)pj * (1.0f / 15.0f);
        const float w00 = (1.0f - ui) * (1.0f - uj), w01 = (1.0f - ui) * uj;
        const float w10 = ui * (1.0f - uj),          w11 = ui * uj;
        const int v0 = complexes[c * 4 + 0], v1 = complexes[c * 4 + 1];
        const int v2 = complexes[c * 4 + 2], v3 = complexes[c * 4 + 3];

        float p[3];
        #pragma unroll
        for (int f = 0; f < 3; ++f)
            p[f] = w00 * points[v0 * 3 + f] + w01 * points[v1 * 3 + f]
                 + w10 * points[v2 * 3 + f] + w11 * points[v3 * 3 + f];

        float Xf[18];
        #pragma unroll
        for (int k = 0; k < ENC; ++k)
            Xf[k] = w00 * encodings[v0 * ENC + k] + w01 * encodings[v1 * ENC + k]
                  + w10 * encodings[v2 * ENC + k] + w11 * encodings[v3 * ENC + k];
        #pragma unroll
        for (int f = 0; f < 3; ++f) Xf[ENC + f] = __sinf(p[f]);   // unscaled

        // write X row (32 bf16 zero-padded), 8-bank swizzle
        #pragma unroll
        for (int ch = 0; ch < 4; ++ch) {
            s16x8 v;
            #pragma unroll
            for (int i = 0; i < 8; ++i) {
                int k = ch * 8 + i;
                v[i] = (k < 18) ? f2bf(Xf[k]) : (short)0;
            }
            *(s16x8*)(Xb + tid * 64 + ((ch * 16) ^ (((tid >> 1) & 3) << 4))) = v;
        }
        WAVE_ORDER();      // X visible (wave-private rows)

        // ---- read X B-frags once ----
        s16x8 bx[4];
        #pragma unroll
        for (int n = 0; n < 4; ++n) {
            int px = wv * 64 + n * 16 + r16;
            bx[n] = *(const s16x8*)(Xb + px * 64 + ((g * 16) ^ (((px >> 1) & 3) << 4)));
        }

        // ---- init layer-2 accumulators with scaled biases ----
        f32x4 acc2[8][4];
        #pragma unroll
        for (int m = 0; m < 8; ++m) {
            f32x4 bv = *(const f32x4*)(b2 + m * 16 + g * 4);
            #pragma unroll
            for (int r = 0; r < 4; ++r) bv[r] *= INV2PI;
            #pragma unroll
            for (int n = 0; n < 4; ++n) acc2[m][n] = bv;
        }

        // ---- prologue: layer-1 pair for ks=0 ----
        f32x4 accp[2][4];
        #pragma unroll
        for (int mm = 0; mm < 2; ++mm) {
            f32x4 bv = *(const f32x4*)(b1 + mm * 16 + g * 4);
            #pragma unroll
            for (int r = 0; r < 4; ++r) bv[r] *= INV2PI;
            #pragma unroll
            for (int n = 0; n < 4; ++n) accp[mm][n] = bv;
            s16x8 a1 = *(const s16x8*)(W1b + (mm * 16 + r16) * 32 + g * 8);
            #pragma unroll
            for (int n = 0; n < 4; ++n)
                accp[mm][n] = __builtin_amdgcn_mfma_f32_16x16x32_bf16(a1, bx[n], accp[mm][n], 0, 0, 0);
        }

        // ---- main ks pipeline (double-buffered h-slices) ----
        #pragma unroll
        for (int ks = 0; ks < 4; ++ks) {
            char* hsl = smem + 32768 + (1 - (ks & 1)) * 16384;

            // h1 slice = sin_act(accp) -> bf16
            s16x4 hv[2][4];
            #pragma unroll
            for (int mm = 0; mm < 2; ++mm)
                #pragma unroll
                for (int n = 0; n < 4; ++n)
                    #pragma unroll
                    for (int r = 0; r < 4; ++r)
                        hv[mm][n][r] = f2bf(sin_act(accp[mm][n][r]));

            #pragma unroll
            for (int mm = 0; mm < 2; ++mm)
                #pragma unroll
                for (int n = 0; n < 4; ++n) {
                    int px = wv * 64 + n * 16 + r16;
                    *(s16x4*)(hsl + px * 64 + ((mm * 32 + g * 8) ^ (((px >> 1) & 3) << 4))) = hv[mm][n];
                }
            WAVE_ORDER();   // same-wave DS RAW; compiler ordering only

            s16x8 hb[4];
            #pragma unroll
            for (int n = 0; n < 4; ++n) {
                int px = wv * 64 + n * 16 + r16;
                hb[n] = *(const s16x8*)(hsl + px * 64 + ((g * 16) ^ (((px >> 1) & 3) << 4)));
            }

            // issue next L1 pair before the L2 bulk (overlap material)
            if (ks < 3) {
                #pragma unroll
                for (int mm = 0; mm < 2; ++mm) {
                    int m1 = (ks + 1) * 2 + mm;
                    f32x4 bv = *(const f32x4*)(b1 + m1 * 16 + g * 4);
                    #pragma unroll
                    for (int r = 0; r < 4; ++r) bv[r] *= INV2PI;
                    #pragma unroll
                    for (int n = 0; n < 4; ++n) accp[mm][n] = bv;
                    s16x8 a1 = *(const s16x8*)(W1b + (m1 * 16 + r16) * 32 + g * 8);
                    #pragma unroll
                    for (int n = 0; n < 4; ++n)
                        accp[mm][n] = __builtin_amdgcn_mfma_f32_16x16x32_bf16(a1, bx[n], accp[mm][n], 0, 0, 0);
                }
            }

            // layer-2 MFMAs; a2 from LDS (swizzled ds_read_b128)
            #pragma unroll
            for (int hf = 0; hf < 2; ++hf) {
                s16x8 a2[4];
                #pragma unroll
                for (int mi = 0; mi < 4; ++mi) {
                    int row = (hf * 4 + mi) * 16 + r16;
                    int L   = row * 256 + ks * 64 + g * 16;
                    a2[mi] = *(const s16x8*)(W2s + (L ^ ((r16 & 7) << 4)));
                }
                #pragma unroll
                for (int mi = 0; mi < 4; ++mi)
                    #pragma unroll
                    for (int n = 0; n < 4; ++n)
                        acc2[hf * 4 + mi][n] = __builtin_amdgcn_mfma_f32_16x16x32_bf16(
                            a2[mi], hb[n], acc2[hf * 4 + mi][n], 0, 0, 0);
            }
        }

        // ---- layer 3 in registers ----
        float pf0[4] = {0.f, 0.f, 0.f, 0.f};
        float pf1[4] = {0.f, 0.f, 0.f, 0.f};
        float pf2[4] = {0.f, 0.f, 0.f, 0.f};
        #pragma unroll
        for (int m = 0; m < 8; ++m) {
            float s2[4][4];
            #pragma unroll
            for (int n = 0; n < 4; ++n)
                #pragma unroll
                for (int r = 0; r < 4; ++r)
                    s2[n][r] = sin_act(acc2[m][n][r]);
            f32x4 w3a = *(const f32x4*)(W3 + 0 * 128 + m * 16 + g * 4);
            f32x4 w3b = *(const f32x4*)(W3 + 1 * 128 + m * 16 + g * 4);
            f32x4 w3c = *(const f32x4*)(W3 + 2 * 128 + m * 16 + g * 4);
            #pragma unroll
            for (int n = 0; n < 4; ++n)
                #pragma unroll
                for (int r = 0; r < 4; ++r) {
                    pf0[n] = fmaf(s2[n][r], w3a[r], pf0[n]);
                    pf1[n] = fmaf(s2[n][r], w3b[r], pf1[n]);
                    pf2[n] = fmaf(s2[n][r], w3c[r], pf2[n]);
                }
        }
        {
            const float b30 = b3[0], b31 = b3[1], b32 = b3[2];
            #pragma unroll
            for (int n = 0; n < 4; ++n) {
                float v0r = pf0[n]; v0r += __shfl_xor(v0r, 16); v0r += __shfl_xor(v0r, 32);
                float v1r = pf1[n]; v1r += __shfl_xor(v1r, 16); v1r += __shfl_xor(v1r, 32);
                float v2r = pf2[n]; v2r += __shfl_xor(v2r, 16); v2r += __shfl_xor(v2r, 32);
                if (g == n) {
                    float x0 = v0r + b30;
                    float x1 = v1r + b31;
                    float x2 = v2r + b32;
                    const int base = (c * 256 + tid) * 3;
                    out0[base + 0] = p[0] + x0;
                    out0[base + 1] = p[1] + x1;
                    out0[base + 2] = p[2] + x2;
                    out1[base + 0] = x0;
                    out1[base + 1] = x1;
                    out1[base + 2] = x2;
                }
            }
        }
    }
    if (blk == 0 && tid == 0) out2[0] = 1.0f;
}

extern "C" void kernel_launch(void* const* d_in, const int* in_sizes, int n_in,
                              void* d_out, int out_size, void* d_ws, size_t ws_size,
                              hipStream_t stream) {
    const float* points    = (const float*)d_in[0];
    const float* encodings = (const float*)d_in[1];
    const float* W1        = (const float*)d_in[2];
    const float* b1        = (const float*)d_in[3];
    const float* W2        = (const float*)d_in[4];
    const float* b2        = (const float*)d_in[5];
    const float* W3        = (const float*)d_in[6];
    const float* b3        = (const float*)d_in[7];
    const int*   complexes = (const int*)d_in[8];

    const int C  = in_sizes[8] / 4;          // 2048
    const int N3 = C * 256 * 3;              // 1,572,864

    float* out0 = (float*)d_out;
    float* out1 = out0 + N3;
    float* out2 = out1 + N3;

    __hip_bfloat16* ws = (__hip_bfloat16*)d_ws;  // needs 40960 B

    NSC_prep_kernel<<<80, 256, 0, stream>>>(W1, W2, ws);
    NSC_59133109732095_kernel<<<C / 2, 256, 0, stream>>>(
        points, encodings, b1, b2, W3, b3, complexes, ws, out0, out1, out2);
}

// Round 20
// 45.018 us; speedup vs baseline: 2.0337x; 1.3580x over previous
//
#include <hip/hip_runtime.h>
#include <hip/hip_bf16.h>

#define ENC 15
#define INV2PI 0.15915494309189535f

typedef __attribute__((ext_vector_type(4))) float f32x4;
typedef __attribute__((ext_vector_type(8))) short s16x8;
typedef __attribute__((ext_vector_type(4))) short s16x4;

static __device__ __forceinline__ short f2bf(float v) {
    __hip_bfloat16 h = __float2bfloat16(v);
    return __builtin_bit_cast(short, h);
}

// Activation sin on PRE-SCALED accumulators: acc already carries the 1/2pi
// factor (folded into W1/W2/b1/b2), so one v_sin_f32 suffices. Using the
// compiler-visible intrinsic (NOT inline asm) so the CDNA4 trans-op
// use-hazard is handled by the compiler — r12's raw-asm version raced.
static __device__ __forceinline__ float sin_act(float x) {
    return __builtin_amdgcn_sinf(x);
}

// Compiler-only ordering (r16-proven): same-wave DS RAW is in-order.
#define WAVE_ORDER() do { \
    asm volatile("" ::: "memory"); \
    __builtin_amdgcn_sched_barrier(0); \
} while (0)

// ---- weight prep ----
// ws (bf16):
//   W1b [128][32] @ 0     = bf16(W1 * INV2PI), k padded 18->32
//   W2s [16384]  @ 4096   = bf16(W2[p ^ s(p)] * INV2PI), s(p)=((p>>7)&7)<<3
//                           (pre-swizzled so linear LDS stage + XOR read = W2)
__global__ void NSC_prep_kernel(const float* __restrict__ W1,
                                const float* __restrict__ W2,
                                __hip_bfloat16* __restrict__ ws) {
    int t = blockIdx.x * 256 + threadIdx.x;
    if (t < 4096) {
        int row = t >> 5, k = t & 31;
        float v = (k < 18) ? W1[row * 18 + k] * INV2PI : 0.0f;
        ws[t] = __float2bfloat16(v);
    } else if (t < 20480) {
        int p = t - 4096;
        int l = p ^ (((p >> 7) & 7) << 3);
        ws[t] = __float2bfloat16(W2[l] * INV2PI);
    }
}

// r17 FINAL (restored verbatim after r18/r19's 2-complex-per-block attempts
// both spilled to scratch — the 128-AGPR + 128-VGPR budget has no headroom
// for loop-carried block state). One block = one complex = 256 px, 4 waves,
// n=4, W2 in LDS (pre-swizzled, 2-way-free ds_read_b128), ks-pipelined
// h-slices (double-buffered, compiler-only fences), 8-bank slice swizzle,
// 1/2pi folded into W1/W2/b1/b2 (single v_sin per activation), layer 3 in
// registers with shfl_xor reduce.
// LDS map: [0,32768) W2s ; [32768,49152) slice0 (X, then h ks=1,3) ;
//          [49152,65536) slice1 (h ks=0,2).
__global__ __launch_bounds__(256, 2)
void NSC_59133109732095_kernel(
    const float* __restrict__ points,
    const float* __restrict__ encodings,
    const float* __restrict__ b1,
    const float* __restrict__ b2,
    const float* __restrict__ W3,
    const float* __restrict__ b3,
    const int*   __restrict__ complexes,
    const __hip_bfloat16* __restrict__ ws,
    float* __restrict__ out0,
    float* __restrict__ out1,
    float* __restrict__ out2)
{
    __shared__ __align__(16) char smem[65536];
    char* W2s = smem;            // 32 KB pre-swizzled W2 (linear stage)
    char* Xb  = smem + 32768;    // slice0: X rows [256][64 B]

    const int c    = blockIdx.x;
    const int tid  = threadIdx.x;
    const int lane = tid & 63;
    const int wv   = tid >> 6;
    const int g    = lane >> 4;
    const int r16  = lane & 15;

    const __hip_bfloat16* W1b = ws;
    const char* ws2b = (const char*)(ws + 4096);

    // ---- stage W2s loads early (hidden under phase 0) ----
    s16x8 stg[8];
    #pragma unroll
    for (int i = 0; i < 8; ++i)
        stg[i] = *(const s16x8*)(ws2b + i * 4096 + tid * 16);

    // ---- phase 0: per-thread bilinear interp, pixel = tid ----
    const int pi = tid >> 4, pj = tid & 15;
    const float ui = (float)pi * (1.0f / 15.0f);
    const float uj = (float)pj * (1.0f / 15.0f);
    const float w00 = (1.0f - ui) * (1.0f - uj), w01 = (1.0f - ui) * uj;
    const float w10 = ui * (1.0f - uj),          w11 = ui * uj;
    const int v0 = complexes[c * 4 + 0], v1 = complexes[c * 4 + 1];
    const int v2 = complexes[c * 4 + 2], v3 = complexes[c * 4 + 3];

    float p[3];
    #pragma unroll
    for (int f = 0; f < 3; ++f)
        p[f] = w00 * points[v0 * 3 + f] + w01 * points[v1 * 3 + f]
             + w10 * points[v2 * 3 + f] + w11 * points[v3 * 3 + f];

    float Xf[18];
    #pragma unroll
    for (int k = 0; k < ENC; ++k)
        Xf[k] = w00 * encodings[v0 * ENC + k] + w01 * encodings[v1 * ENC + k]
              + w10 * encodings[v2 * ENC + k] + w11 * encodings[v3 * ENC + k];
    #pragma unroll
    for (int f = 0; f < 3; ++f) Xf[ENC + f] = __sinf(p[f]);   // unscaled input

    // write X row (32 bf16 zero-padded), 8-bank swizzle
    #pragma unroll
    for (int ch = 0; ch < 4; ++ch) {
        s16x8 v;
        #pragma unroll
        for (int i = 0; i < 8; ++i) {
            int k = ch * 8 + i;
            v[i] = (k < 18) ? f2bf(Xf[k]) : (short)0;
        }
        *(s16x8*)(Xb + tid * 64 + ((ch * 16) ^ (((tid >> 1) & 3) << 4))) = v;
    }

    // write staged W2 chunks (linear)
    #pragma unroll
    for (int i = 0; i < 8; ++i)
        *(s16x8*)(W2s + i * 4096 + tid * 16) = stg[i];

    __syncthreads();   // W2s (block-shared) + X visible

    // ---- read X B-frags once ----
    s16x8 bx[4];
    #pragma unroll
    for (int n = 0; n < 4; ++n) {
        int px = wv * 64 + n * 16 + r16;
        bx[n] = *(const s16x8*)(Xb + px * 64 + ((g * 16) ^ (((px >> 1) & 3) << 4)));
    }

    // ---- init layer-2 accumulators with scaled biases ----
    f32x4 acc2[8][4];
    #pragma unroll
    for (int m = 0; m < 8; ++m) {
        f32x4 bv = *(const f32x4*)(b2 + m * 16 + g * 4);
        #pragma unroll
        for (int r = 0; r < 4; ++r) bv[r] *= INV2PI;
        #pragma unroll
        for (int n = 0; n < 4; ++n) acc2[m][n] = bv;
    }

    // ---- prologue: layer-1 pair for ks=0 ----
    f32x4 accp[2][4];
    #pragma unroll
    for (int mm = 0; mm < 2; ++mm) {
        f32x4 bv = *(const f32x4*)(b1 + mm * 16 + g * 4);
        #pragma unroll
        for (int r = 0; r < 4; ++r) bv[r] *= INV2PI;
        #pragma unroll
        for (int n = 0; n < 4; ++n) accp[mm][n] = bv;
        s16x8 a1 = *(const s16x8*)(W1b + (mm * 16 + r16) * 32 + g * 8);
        #pragma unroll
        for (int n = 0; n < 4; ++n)
            accp[mm][n] = __builtin_amdgcn_mfma_f32_16x16x32_bf16(a1, bx[n], accp[mm][n], 0, 0, 0);
    }

    // ---- main ks pipeline (double-buffered h-slices, compiler-only order) ----
    #pragma unroll
    for (int ks = 0; ks < 4; ++ks) {
        char* hsl = smem + 32768 + (1 - (ks & 1)) * 16384;

        // h1 slice = sin_act(accp) -> bf16  (accp carries 1/2pi)
        s16x4 hv[2][4];
        #pragma unroll
        for (int mm = 0; mm < 2; ++mm)
            #pragma unroll
            for (int n = 0; n < 4; ++n)
                #pragma unroll
                for (int r = 0; r < 4; ++r)
                    hv[mm][n][r] = f2bf(sin_act(accp[mm][n][r]));

        #pragma unroll
        for (int mm = 0; mm < 2; ++mm)
            #pragma unroll
            for (int n = 0; n < 4; ++n) {
                int px = wv * 64 + n * 16 + r16;
                *(s16x4*)(hsl + px * 64 + ((mm * 32 + g * 8) ^ (((px >> 1) & 3) << 4))) = hv[mm][n];
            }
        WAVE_ORDER();   // same-wave DS RAW is in-order; compiler ordering only

        s16x8 hb[4];
        #pragma unroll
        for (int n = 0; n < 4; ++n) {
            int px = wv * 64 + n * 16 + r16;
            hb[n] = *(const s16x8*)(hsl + px * 64 + ((g * 16) ^ (((px >> 1) & 3) << 4)));
        }

        // issue next L1 pair before the L2 bulk (overlap material)
        if (ks < 3) {
            #pragma unroll
            for (int mm = 0; mm < 2; ++mm) {
                int m1 = (ks + 1) * 2 + mm;
                f32x4 bv = *(const f32x4*)(b1 + m1 * 16 + g * 4);
                #pragma unroll
                for (int r = 0; r < 4; ++r) bv[r] *= INV2PI;
                #pragma unroll
                for (int n = 0; n < 4; ++n) accp[mm][n] = bv;
                s16x8 a1 = *(const s16x8*)(W1b + (m1 * 16 + r16) * 32 + g * 8);
                #pragma unroll
                for (int n = 0; n < 4; ++n)
                    accp[mm][n] = __builtin_amdgcn_mfma_f32_16x16x32_bf16(a1, bx[n], accp[mm][n], 0, 0, 0);
            }
        }

        // layer-2 MFMAs; a2 from LDS (swizzled ds_read_b128)
        #pragma unroll
        for (int hf = 0; hf < 2; ++hf) {
            s16x8 a2[4];
            #pragma unroll
            for (int mi = 0; mi < 4; ++mi) {
                int row = (hf * 4 + mi) * 16 + r16;
                int L   = row * 256 + ks * 64 + g * 16;
                a2[mi] = *(const s16x8*)(W2s + (L ^ ((r16 & 7) << 4)));
            }
            #pragma unroll
            for (int mi = 0; mi < 4; ++mi)
                #pragma unroll
                for (int n = 0; n < 4; ++n)
                    acc2[hf * 4 + mi][n] = __builtin_amdgcn_mfma_f32_16x16x32_bf16(
                        a2[mi], hb[n], acc2[hf * 4 + mi][n], 0, 0, 0);
        }
    }

    // ---- layer 3 in registers: x[f][px] = sum_j W3[f][j]*sin_act(acc2_j) ----
    float pf0[4] = {0.f, 0.f, 0.f, 0.f};
    float pf1[4] = {0.f, 0.f, 0.f, 0.f};
    float pf2[4] = {0.f, 0.f, 0.f, 0.f};
    #pragma unroll
    for (int m = 0; m < 8; ++m) {
        float s2[4][4];
        #pragma unroll
        for (int n = 0; n < 4; ++n)
            #pragma unroll
            for (int r = 0; r < 4; ++r)
                s2[n][r] = sin_act(acc2[m][n][r]);   // acc2 carries 1/2pi
        f32x4 w3a = *(const f32x4*)(W3 + 0 * 128 + m * 16 + g * 4);
        f32x4 w3b = *(const f32x4*)(W3 + 1 * 128 + m * 16 + g * 4);
        f32x4 w3c = *(const f32x4*)(W3 + 2 * 128 + m * 16 + g * 4);
        #pragma unroll
        for (int n = 0; n < 4; ++n)
            #pragma unroll
            for (int r = 0; r < 4; ++r) {
                pf0[n] = fmaf(s2[n][r], w3a[r], pf0[n]);
                pf1[n] = fmaf(s2[n][r], w3b[r], pf1[n]);
                pf2[n] = fmaf(s2[n][r], w3c[r], pf2[n]);
            }
    }
    {
        const float b30 = b3[0], b31 = b3[1], b32 = b3[2];
        #pragma unroll
        for (int n = 0; n < 4; ++n) {
            float v0r = pf0[n]; v0r += __shfl_xor(v0r, 16); v0r += __shfl_xor(v0r, 32);
            float v1r = pf1[n]; v1r += __shfl_xor(v1r, 16); v1r += __shfl_xor(v1r, 32);
            float v2r = pf2[n]; v2r += __shfl_xor(v2r, 16); v2r += __shfl_xor(v2r, 32);
            if (g == n) {
                float x0 = v0r + b30;
                float x1 = v1r + b31;
                float x2 = v2r + b32;
                const int base = (c * 256 + tid) * 3;
                out0[base + 0] = p[0] + x0;
                out0[base + 1] = p[1] + x1;
                out0[base + 2] = p[2] + x2;
                out1[base + 0] = x0;
                out1[base + 1] = x1;
                out1[base + 2] = x2;
            }
        }
    }
    if (c == 0 && tid == 0) out2[0] = 1.0f;
}

extern "C" void kernel_launch(void* const* d_in, const int* in_sizes, int n_in,
                              void* d_out, int out_size, void* d_ws, size_t ws_size,
                              hipStream_t stream) {
    const float* points    = (const float*)d_in[0];
    const float* encodings = (const float*)d_in[1];
    const float* W1        = (const float*)d_in[2];
    const float* b1        = (const float*)d_in[3];
    const float* W2        = (const float*)d_in[4];
    const float* b2        = (const float*)d_in[5];
    const float* W3        = (const float*)d_in[6];
    const float* b3        = (const float*)d_in[7];
    const int*   complexes = (const int*)d_in[8];

    const int C  = in_sizes[8] / 4;          // 2048
    const int N3 = C * 256 * 3;              // 1,572,864

    float* out0 = (float*)d_out;
    float* out1 = out0 + N3;
    float* out2 = out1 + N3;

    __hip_bfloat16* ws = (__hip_bfloat16*)d_ws;  // needs 40960 B

    NSC_prep_kernel<<<80, 256, 0, stream>>>(W1, W2, ws);
    NSC_59133109732095_kernel<<<C, 256, 0, stream>>>(
        points, encodings, b1, b2, W3, b3, complexes, ws, out0, out1, out2);
}